// Round 3
// baseline (128.759 us; speedup 1.0000x reference)
//
#include <hip/hip_runtime.h>
#include <hip/hip_bf16.h>
#include <stdint.h>

#define BATCH 2048
#define NNODE 4096
#define TDIM  2048
#define NCLS  10
#define WDIM  64

// ---------------- ws[k] = sum_w W[w][k] ----------------
__global__ void k_wsum(const float* __restrict__ w_sub, const float* __restrict__ w_inter,
                       float* __restrict__ wsum_sub, float* __restrict__ wsum_inter) {
  int k = blockIdx.x * blockDim.x + threadIdx.x;
  if (k >= TDIM) return;
  float a = 0.f, b = 0.f;
  for (int w = 0; w < WDIM; ++w) {
    a += w_sub[w * TDIM + k];
    b += w_inter[w * TDIM + k];
  }
  wsum_sub[k] = a; wsum_inter[k] = b;
}

// ---------------- g[n] = gem[n,:] . wsum  (one wave per n) ----------------
__global__ void k_gvec(const float* __restrict__ gem, const float* __restrict__ wsum_sub,
                       const float* __restrict__ wsum_inter,
                       float* __restrict__ g_sub, float* __restrict__ g_inter) {
  int wid = threadIdx.x >> 6, lane = threadIdx.x & 63;
  int n = blockIdx.x * 4 + wid;
  const float* row = gem + (size_t)n * TDIM;
  float a = 0.f, b = 0.f;
  for (int k = lane; k < TDIM; k += 64) {
    float g = row[k];
    a += g * wsum_sub[k];
    b += g * wsum_inter[k];
  }
  #pragma unroll
  for (int off = 32; off > 0; off >>= 1) {
    a += __shfl_down(a, off, 64);
    b += __shfl_down(b, off, 64);
  }
  if (lane == 0) { g_sub[n] = a; g_inter[n] = b; }
}

// ---------------- cvec[n] = (1 - adj[m_n][m_n]) * g_sub[m_n] ----------------
__global__ void k_cvec(const int* __restrict__ adj, const int* __restrict__ mask_idx,
                       const float* __restrict__ g_sub, float* __restrict__ cvec) {
  int n = blockIdx.x * blockDim.x + threadIdx.x;
  if (n >= BATCH) return;
  int m = mask_idx[n];
  cvec[n] = adj[(size_t)m * NNODE + m] ? 0.f : g_sub[m];
}

// ---------------- counts -> invN, s[p] = pred[p, t_p] ----------------
__global__ void k_stats(const float* __restrict__ pred, const int* __restrict__ target,
                        float* __restrict__ invN, float* __restrict__ svec) {
  __shared__ int cnt[NCLS];
  int tid = threadIdx.x;  // 1024
  if (tid < NCLS) cnt[tid] = 0;
  __syncthreads();
  for (int b = tid; b < BATCH; b += 1024) atomicAdd(&cnt[target[b]], 1);
  __syncthreads();
  for (int b = tid; b < BATCH; b += 1024) {
    int t = target[b];
    invN[b] = 1.f / (float)cnt[t];
    svec[b] = pred[b * NCLS + t];
  }
}

// ------- AdjTb[k][w] = bits of adj[mask_idx[n]][k] for n = 32w..32w+31 -------
__global__ void k_transpose(const int* __restrict__ adj, const int* __restrict__ mask_idx,
                            unsigned int* __restrict__ AdjTb) {
  __shared__ unsigned char tile[64][80];  // pitch 80: 16B-aligned rows, broken bank stride
  int tid = threadIdx.x;
  int kt = blockIdx.x & 63;   // 64 k-tiles (4096/64)
  int nt = blockIdx.x >> 6;   // 32 n-tiles (2048/64)
  int nl = tid >> 2;          // 0..63
  int kl = (tid & 3) * 16;    // 0,16,32,48
  int row = mask_idx[nt * 64 + nl];
  const uint4* src = (const uint4*)(adj + (size_t)row * NNODE + kt * 64 + kl);
  unsigned char o[16];
  #pragma unroll
  for (int q = 0; q < 4; ++q) {
    uint4 v = src[q];
    o[q * 4 + 0] = v.x ? 1 : 0;
    o[q * 4 + 1] = v.y ? 1 : 0;
    o[q * 4 + 2] = v.z ? 1 : 0;
    o[q * 4 + 3] = v.w ? 1 : 0;
  }
  *(uint4*)&tile[nl][kl] = *(uint4*)o;
  __syncthreads();
  if (tid < 128) {
    int kl2 = tid >> 1;       // 0..63
    int half = tid & 1;       // which 32-n group
    unsigned int bits = 0;
    #pragma unroll
    for (int j = 0; j < 32; ++j)
      bits |= (tile[half * 32 + j][kl2] ? 1u : 0u) << j;
    AdjTb[(size_t)(kt * 64 + kl2) * (BATCH / 32) + nt * 2 + half] = bits;
  }
}

// ---------------- fused: neighbor scan -> sparse scatter -> loss epilogue ----------------
__global__ __launch_bounds__(256) void k_main(
    const int* __restrict__ adj, const unsigned int* __restrict__ AdjTb,
    const int* __restrict__ mask_idx, const int* __restrict__ target,
    const float* __restrict__ g_sub, const float* __restrict__ g_inter,
    const float* __restrict__ cvec, const float* __restrict__ invN,
    const float* __restrict__ svec, const float* __restrict__ pred,
    float* __restrict__ partial) {
  __shared__ float S1[2304];   // S_sub row, addr(n) = n + n/8
  __shared__ float S2[2304];   // S_inter row
  __shared__ unsigned short list_s[512];
  __shared__ float gls[512], gli[512];
  __shared__ unsigned short abit16[256];
  __shared__ int wcnt[4];
  __shared__ float wred[4];
  __shared__ float rowsum_sh;
  __shared__ int total_sh;

  int tid = threadIdx.x, p = blockIdx.x;
  int lane = tid & 63, wid = tid >> 6;
  int mp = mask_idx[p];

  // --- step 0: scan p's adjacency row (16 int32 / thread) ---
  const uint4* a4 = (const uint4*)(adj + (size_t)mp * NNODE) + tid * 4;
  unsigned int mybits = 0; int cnt = 0;
  #pragma unroll
  for (int q = 0; q < 4; ++q) {
    uint4 v = a4[q];
    if (v.x) { mybits |= 1u << (q * 4 + 0); ++cnt; }
    if (v.y) { mybits |= 1u << (q * 4 + 1); ++cnt; }
    if (v.z) { mybits |= 1u << (q * 4 + 2); ++cnt; }
    if (v.w) { mybits |= 1u << (q * 4 + 3); ++cnt; }
  }
  abit16[tid] = (unsigned short)mybits;

  // --- exclusive scan of per-thread counts (deterministic list order) ---
  int incl = cnt;
  #pragma unroll
  for (int d = 1; d < 64; d <<= 1) {
    int y = __shfl_up(incl, d, 64);
    if (lane >= d) incl += y;
  }
  if (lane == 63) wcnt[wid] = incl;
  __syncthreads();                       // barrier 1
  int wbase = 0;
  for (int w = 0; w < wid; ++w) wbase += wcnt[w];
  int off = wbase + incl - cnt;
  #pragma unroll
  for (int j = 0; j < 16; ++j)
    if (mybits & (1u << j)) { if (off < 512) list_s[off] = (unsigned short)(tid * 16 + j); ++off; }
  if (tid == 0) total_sh = wcnt[0] + wcnt[1] + wcnt[2] + wcnt[3];

  // zero S accumulators
  for (int i = tid; i < 2304; i += 256) { S1[i] = 0.f; S2[i] = 0.f; }
  __syncthreads();                       // barrier 2
  int total = total_sh;
  if (total > 512) total = 512;

  // --- stage g values for the list; rowsum = sum g_sub over neighbors ---
  float rl = 0.f;
  for (int i = tid; i < total; i += 256) {
    int k = list_s[i];
    float gs = g_sub[k], gi = g_inter[k];
    gls[i] = gs; gli[i] = gi;
    rl += gs;
  }
  #pragma unroll
  for (int o = 32; o > 0; o >>= 1) rl += __shfl_down(rl, o, 64);
  if (lane == 0) wred[wid] = rl;
  __syncthreads();                       // barrier 3
  if (tid == 0) rowsum_sh = wred[0] + wred[1] + wred[2] + wred[3];
  __syncthreads();                       // barrier 4

  // --- sparse scatter: for each neighbor k, S[n] += g[k] where A[n,k]=1 ---
  for (int it = 0; it < total; ++it) {
    int k = list_s[it];
    unsigned int word = AdjTb[(size_t)k * (BATCH / 32) + (tid >> 2)];
    unsigned int byte = (word >> ((tid & 3) * 8)) & 0xFFu;
    if (byte) {
      float gs = gls[it], gi = gli[it];
      while (byte) {
        int j = __ffs(byte) - 1;
        byte &= byte - 1;
        int a = 9 * tid + j;             // addr(n = tid*8+j) = n + n/8
        S1[a] += gs; S2[a] += gi;
      }
    }
  }
  __syncthreads();                       // barrier 5

  // --- loss epilogue over this row ---
  int tp = target[p];
  float sp = svec[p], ip = invN[p], rs = rowsum_sh;
  float acc = 0.f;
  #pragma unroll
  for (int j = 0; j < 8; ++j) {
    int n = tid * 8 + j;
    int tn = target[n];
    if (tn == tp) continue;
    int mn = mask_idx[n];
    float apn = ((abit16[mn >> 4] >> (mn & 15)) & 1) ? 1.f : 0.f;
    float Ssub = S1[9 * tid + j];
    float Sint = S2[9 * tid + j];
    float vs = rs - Ssub - apn * cvec[n];
    float r = (1.f + vs) / (1.f + Sint);
    float v = 1.f / (1.f + expf(r));     // 1 - sigmoid(r)
    float cross = pred[n * NCLS + tp];
    float d = 1.f - (sp - cross);
    acc += ip * invN[n] * v * d * d;
  }
  #pragma unroll
  for (int o = 32; o > 0; o >>= 1) acc += __shfl_down(acc, o, 64);
  if (lane == 0) wred[wid] = acc;
  __syncthreads();
  if (tid == 0) partial[p] = wred[0] + wred[1] + wred[2] + wred[3];
}

__global__ void k_final(const float* __restrict__ partial, float* __restrict__ out) {
  int tid = threadIdx.x;  // 256
  float local = 0.f;
  for (int p = tid; p < BATCH; p += 256) local += partial[p];
  __shared__ float red[4];
  #pragma unroll
  for (int off = 32; off > 0; off >>= 1) local += __shfl_down(local, off, 64);
  if ((tid & 63) == 0) red[tid >> 6] = local;
  __syncthreads();
  if (tid == 0) out[0] = red[0] + red[1] + red[2] + red[3];
}

extern "C" void kernel_launch(void* const* d_in, const int* in_sizes, int n_in,
                              void* d_out, int out_size, void* d_ws, size_t ws_size,
                              hipStream_t stream) {
  const float* pred    = (const float*)d_in[0];
  const float* gem     = (const float*)d_in[1];
  const float* w_sub   = (const float*)d_in[2];
  const float* w_inter = (const float*)d_in[3];
  // d_in[4] = w_global (unused by the loss)
  const int* adj       = (const int*)d_in[5];   // bool in reference -> int32 in harness
  const int* target    = (const int*)d_in[6];
  const int* mask_idx  = (const int*)d_in[7];
  float* out = (float*)d_out;

  char* ws = (char*)d_ws;
  size_t off = 0;
  auto alloc = [&](size_t bytes) {
    void* p = ws + off;
    off = (off + bytes + 255) & ~(size_t)255;
    return p;
  };
  unsigned int* AdjTb = (unsigned int*)alloc((size_t)NNODE * (BATCH / 32) * 4);  // 1 MB
  float* g_sub     = (float*)alloc((size_t)NNODE * 4);
  float* g_inter   = (float*)alloc((size_t)NNODE * 4);
  float* wsum_sub  = (float*)alloc((size_t)TDIM * 4);
  float* wsum_inter= (float*)alloc((size_t)TDIM * 4);
  float* cvec      = (float*)alloc((size_t)BATCH * 4);
  float* invN      = (float*)alloc((size_t)BATCH * 4);
  float* svec      = (float*)alloc((size_t)BATCH * 4);
  float* partial   = (float*)alloc((size_t)BATCH * 4);

  k_wsum<<<(TDIM + 255) / 256, 256, 0, stream>>>(w_sub, w_inter, wsum_sub, wsum_inter);
  k_gvec<<<NNODE / 4, 256, 0, stream>>>(gem, wsum_sub, wsum_inter, g_sub, g_inter);
  k_cvec<<<(BATCH + 255) / 256, 256, 0, stream>>>(adj, mask_idx, g_sub, cvec);
  k_stats<<<1, 1024, 0, stream>>>(pred, target, invN, svec);
  k_transpose<<<(NNODE / 64) * (BATCH / 64), 256, 0, stream>>>(adj, mask_idx, AdjTb);
  k_main<<<BATCH, 256, 0, stream>>>(adj, AdjTb, mask_idx, target, g_sub, g_inter,
                                    cvec, invN, svec, pred, partial);
  k_final<<<1, 256, 0, stream>>>(partial, out);
}

// Round 4
// 94.195 us; speedup vs baseline: 1.3669x; 1.3669x over previous
//
#include <hip/hip_runtime.h>
#include <hip/hip_bf16.h>
#include <stdint.h>

#define BATCH 2048
#define NNODE 4096
#define TDIM  2048
#define NCLS  10
#define WDIM  64

// ---------------- ws[k] = sum_w W[w][k] ----------------
__global__ void k_wsum(const float* __restrict__ w_sub, const float* __restrict__ w_inter,
                       float* __restrict__ wsum_sub, float* __restrict__ wsum_inter) {
  int k = blockIdx.x * blockDim.x + threadIdx.x;
  if (k >= TDIM) return;
  float a = 0.f, b = 0.f;
  for (int w = 0; w < WDIM; ++w) {
    a += w_sub[w * TDIM + k];
    b += w_inter[w * TDIM + k];
  }
  wsum_sub[k] = a; wsum_inter[k] = b;
}

// ---------------- g[n] = gem[n,:] . wsum  (one wave per n, float4) ----------------
__global__ void k_gvec(const float* __restrict__ gem, const float* __restrict__ wsum_sub,
                       const float* __restrict__ wsum_inter,
                       float* __restrict__ g_sub, float* __restrict__ g_inter) {
  int wid = threadIdx.x >> 6, lane = threadIdx.x & 63;
  int n = blockIdx.x * 4 + wid;
  const float4* row = (const float4*)(gem + (size_t)n * TDIM);
  const float4* ws4 = (const float4*)wsum_sub;
  const float4* wi4 = (const float4*)wsum_inter;
  float a = 0.f, b = 0.f;
  #pragma unroll
  for (int s = 0; s < TDIM / 256; ++s) {   // 8 steps of 64 lanes x float4
    int idx = s * 64 + lane;
    float4 g = row[idx], u = ws4[idx], v = wi4[idx];
    a += g.x * u.x + g.y * u.y + g.z * u.z + g.w * u.w;
    b += g.x * v.x + g.y * v.y + g.z * v.z + g.w * v.w;
  }
  #pragma unroll
  for (int off = 32; off > 0; off >>= 1) {
    a += __shfl_down(a, off, 64);
    b += __shfl_down(b, off, 64);
  }
  if (lane == 0) { g_sub[n] = a; g_inter[n] = b; }
}

// ------- fused per-batch small stuff: class counts -> invN, svec, cvec -------
__global__ void k_misc(const float* __restrict__ pred, const int* __restrict__ target,
                       const int* __restrict__ mask_idx, const int* __restrict__ adj,
                       const float* __restrict__ g_sub,
                       float* __restrict__ invN, float* __restrict__ svec,
                       float* __restrict__ cvec) {
  __shared__ int cnt[NCLS];
  int tid = threadIdx.x, lane = tid & 63;
  if (tid < NCLS) cnt[tid] = 0;
  __syncthreads();
  for (int i = 0; i < BATCH / 256; ++i) {
    int t = target[tid + i * 256];
    #pragma unroll
    for (int c = 0; c < NCLS; ++c) {
      unsigned long long m = __ballot(t == c);
      if (lane == 0 && m) atomicAdd(&cnt[c], __popcll(m));
    }
  }
  __syncthreads();
  int n = blockIdx.x * 256 + tid;  // grid = 8 blocks
  int t = target[n];
  invN[n] = 1.f / (float)cnt[t];
  svec[n] = pred[n * NCLS + t];
  int m = mask_idx[n];
  cvec[n] = adj[(size_t)m * NNODE + m] ? 0.f : g_sub[m];
}

// ------- AdjTb[k][w] = bits of adj[mask_idx[n]][k] for n = 32w..32w+31 -------
__global__ void k_transpose(const int* __restrict__ adj, const int* __restrict__ mask_idx,
                            unsigned int* __restrict__ AdjTb) {
  __shared__ unsigned char tile[64][80];
  int tid = threadIdx.x;
  int kt = blockIdx.x & 63;   // 64 k-tiles (4096/64)
  int nt = blockIdx.x >> 6;   // 32 n-tiles (2048/64)
  int nl = tid >> 2;          // 0..63
  int kl = (tid & 3) * 16;    // 0,16,32,48
  int row = mask_idx[nt * 64 + nl];
  const uint4* src = (const uint4*)(adj + (size_t)row * NNODE + kt * 64 + kl);
  unsigned char o[16];
  #pragma unroll
  for (int q = 0; q < 4; ++q) {
    uint4 v = src[q];
    o[q * 4 + 0] = v.x ? 1 : 0;
    o[q * 4 + 1] = v.y ? 1 : 0;
    o[q * 4 + 2] = v.z ? 1 : 0;
    o[q * 4 + 3] = v.w ? 1 : 0;
  }
  *(uint4*)&tile[nl][kl] = *(uint4*)o;
  __syncthreads();
  if (tid < 128) {
    int kl2 = tid >> 1;       // 0..63
    int half = tid & 1;       // which 32-n group
    unsigned int bits = 0;
    #pragma unroll
    for (int j = 0; j < 32; ++j)
      bits |= (tile[half * 32 + j][kl2] ? 1u : 0u) << j;
    AdjTb[(size_t)(kt * 64 + kl2) * (BATCH / 32) + nt * 2 + half] = bits;
  }
}

// ---------------- fused: neighbor scan -> pipelined sparse scatter -> loss ----------------
__global__ __launch_bounds__(256) void k_main(
    const int* __restrict__ adj, const unsigned int* __restrict__ AdjTb,
    const int* __restrict__ mask_idx, const int* __restrict__ target,
    const float* __restrict__ g_sub, const float* __restrict__ g_inter,
    const float* __restrict__ cvec, const float* __restrict__ invN,
    const float* __restrict__ svec, const float* __restrict__ pred,
    float* __restrict__ partial) {
  __shared__ float S1[2304];   // S_sub row, addr(n) = n + n/8
  __shared__ float S2[2304];   // S_inter row
  __shared__ unsigned short list_s[512];
  __shared__ float gls[512], gli[512];
  __shared__ unsigned short abit16[256];
  __shared__ int wcnt[4];
  __shared__ float wred[4];
  __shared__ float rowsum_sh;
  __shared__ int total_sh;

  int tid = threadIdx.x, p = blockIdx.x;
  int lane = tid & 63, wid = tid >> 6;
  int mp = mask_idx[p];

  // --- scan p's adjacency row (16 int32 / thread) ---
  const uint4* a4 = (const uint4*)(adj + (size_t)mp * NNODE) + tid * 4;
  unsigned int mybits = 0; int cnt = 0;
  #pragma unroll
  for (int q = 0; q < 4; ++q) {
    uint4 v = a4[q];
    if (v.x) { mybits |= 1u << (q * 4 + 0); ++cnt; }
    if (v.y) { mybits |= 1u << (q * 4 + 1); ++cnt; }
    if (v.z) { mybits |= 1u << (q * 4 + 2); ++cnt; }
    if (v.w) { mybits |= 1u << (q * 4 + 3); ++cnt; }
  }
  abit16[tid] = (unsigned short)mybits;

  // --- exclusive scan of per-thread counts (deterministic list order) ---
  int incl = cnt;
  #pragma unroll
  for (int d = 1; d < 64; d <<= 1) {
    int y = __shfl_up(incl, d, 64);
    if (lane >= d) incl += y;
  }
  if (lane == 63) wcnt[wid] = incl;
  __syncthreads();                       // barrier 1
  int wbase = 0;
  for (int w = 0; w < wid; ++w) wbase += wcnt[w];
  int off = wbase + incl - cnt;
  #pragma unroll
  for (int j = 0; j < 16; ++j)
    if (mybits & (1u << j)) { if (off < 512) list_s[off] = (unsigned short)(tid * 16 + j); ++off; }
  if (tid == 0) total_sh = wcnt[0] + wcnt[1] + wcnt[2] + wcnt[3];

  // zero S accumulators
  for (int i = tid; i < 2304; i += 256) { S1[i] = 0.f; S2[i] = 0.f; }
  __syncthreads();                       // barrier 2
  int total = total_sh;
  if (total > 512) total = 512;

  // --- stage g values; rowsum = sum g_sub over neighbors ---
  float rl = 0.f;
  for (int i = tid; i < total; i += 256) {
    int k = list_s[i];
    float gs = g_sub[k], gi = g_inter[k];
    gls[i] = gs; gli[i] = gi;
    rl += gs;
  }
  #pragma unroll
  for (int o = 32; o > 0; o >>= 1) rl += __shfl_down(rl, o, 64);
  if (lane == 0) wred[wid] = rl;
  __syncthreads();                       // barrier 3
  if (tid == 0) rowsum_sh = wred[0] + wred[1] + wred[2] + wred[3];
  __syncthreads();                       // barrier 4

  // --- sparse scatter, software-pipelined 8-deep ---
  int sh = (tid & 3) * 8;
  for (int it0 = 0; it0 < total; it0 += 8) {
    unsigned int wv[8];
    #pragma unroll
    for (int u = 0; u < 8; ++u) {
      int it = it0 + u; if (it >= total) it = total - 1;
      wv[u] = AdjTb[(size_t)list_s[it] * (BATCH / 32) + (tid >> 2)];
    }
    #pragma unroll
    for (int u = 0; u < 8; ++u) {
      int it = it0 + u;
      if (it < total) {
        unsigned int byte = (wv[u] >> sh) & 0xFFu;
        if (byte) {
          float gs = gls[it], gi = gli[it];
          while (byte) {
            int j = __ffs(byte) - 1;
            byte &= byte - 1;
            int a = 9 * tid + j;         // addr(n = tid*8+j) = n + n/8
            S1[a] += gs; S2[a] += gi;
          }
        }
      }
    }
  }
  __syncthreads();                       // barrier 5

  // --- loss epilogue over this row (vectorized loads) ---
  int tp = target[p];
  float sp = svec[p], ip = invN[p], rs = rowsum_sh;
  int tn[8], mn[8];
  float iN[8];
  *(int4*)(tn)     = *(const int4*)&target[tid * 8];
  *(int4*)(tn + 4) = *(const int4*)&target[tid * 8 + 4];
  *(int4*)(mn)     = *(const int4*)&mask_idx[tid * 8];
  *(int4*)(mn + 4) = *(const int4*)&mask_idx[tid * 8 + 4];
  *(float4*)(iN)     = *(const float4*)&invN[tid * 8];
  *(float4*)(iN + 4) = *(const float4*)&invN[tid * 8 + 4];
  float acc = 0.f;
  #pragma unroll
  for (int j = 0; j < 8; ++j) {
    int n = tid * 8 + j;
    if (tn[j] == tp) continue;
    float apn = ((abit16[mn[j] >> 4] >> (mn[j] & 15)) & 1) ? 1.f : 0.f;
    float Ssub = S1[9 * tid + j];
    float Sint = S2[9 * tid + j];
    float vs = rs - Ssub - apn * cvec[n];
    float r = (1.f + vs) / (1.f + Sint);
    float v = 1.f / (1.f + __expf(r));   // 1 - sigmoid(r)
    float cross = pred[n * NCLS + tp];
    float d = 1.f - (sp - cross);
    acc += ip * iN[j] * v * d * d;
  }
  #pragma unroll
  for (int o = 32; o > 0; o >>= 1) acc += __shfl_down(acc, o, 64);
  if (lane == 0) wred[wid] = acc;
  __syncthreads();
  if (tid == 0) partial[p] = wred[0] + wred[1] + wred[2] + wred[3];
}

__global__ void k_final(const float* __restrict__ partial, float* __restrict__ out) {
  int tid = threadIdx.x;  // 256
  float local = 0.f;
  for (int p = tid; p < BATCH; p += 256) local += partial[p];
  __shared__ float red[4];
  #pragma unroll
  for (int off = 32; off > 0; off >>= 1) local += __shfl_down(local, off, 64);
  if ((tid & 63) == 0) red[tid >> 6] = local;
  __syncthreads();
  if (tid == 0) out[0] = red[0] + red[1] + red[2] + red[3];
}

extern "C" void kernel_launch(void* const* d_in, const int* in_sizes, int n_in,
                              void* d_out, int out_size, void* d_ws, size_t ws_size,
                              hipStream_t stream) {
  const float* pred    = (const float*)d_in[0];
  const float* gem     = (const float*)d_in[1];
  const float* w_sub   = (const float*)d_in[2];
  const float* w_inter = (const float*)d_in[3];
  // d_in[4] = w_global (unused by the loss)
  const int* adj       = (const int*)d_in[5];   // bool in reference -> int32 in harness
  const int* target    = (const int*)d_in[6];
  const int* mask_idx  = (const int*)d_in[7];
  float* out = (float*)d_out;

  char* ws = (char*)d_ws;
  size_t off = 0;
  auto alloc = [&](size_t bytes) {
    void* p = ws + off;
    off = (off + bytes + 255) & ~(size_t)255;
    return p;
  };
  unsigned int* AdjTb = (unsigned int*)alloc((size_t)NNODE * (BATCH / 32) * 4);  // 1 MB
  float* g_sub     = (float*)alloc((size_t)NNODE * 4);
  float* g_inter   = (float*)alloc((size_t)NNODE * 4);
  float* wsum_sub  = (float*)alloc((size_t)TDIM * 4);
  float* wsum_inter= (float*)alloc((size_t)TDIM * 4);
  float* cvec      = (float*)alloc((size_t)BATCH * 4);
  float* invN      = (float*)alloc((size_t)BATCH * 4);
  float* svec      = (float*)alloc((size_t)BATCH * 4);
  float* partial   = (float*)alloc((size_t)BATCH * 4);

  k_wsum<<<(TDIM + 255) / 256, 256, 0, stream>>>(w_sub, w_inter, wsum_sub, wsum_inter);
  k_gvec<<<NNODE / 4, 256, 0, stream>>>(gem, wsum_sub, wsum_inter, g_sub, g_inter);
  k_transpose<<<(NNODE / 64) * (BATCH / 64), 256, 0, stream>>>(adj, mask_idx, AdjTb);
  k_misc<<<BATCH / 256, 256, 0, stream>>>(pred, target, mask_idx, adj, g_sub,
                                          invN, svec, cvec);
  k_main<<<BATCH, 256, 0, stream>>>(adj, AdjTb, mask_idx, target, g_sub, g_inter,
                                    cvec, invN, svec, pred, partial);
  k_final<<<1, 256, 0, stream>>>(partial, out);
}